// Round 8
// baseline (33.227 us; speedup 1.0000x reference)
//
#include <hip/hip_runtime.h>
#include <math.h>

#define CUTOFF 5.0f

#define N_SYS 8
#define N_AT  1024
#define EPS   (N_AT * (N_AT - 1))   // 1047552 edges per system

// ---- producer-consumer geometry: 4P + 4C, raw-barrier pipeline ----
#define BLOCKT 512                  // 8 waves: 4 producers + 4 consumers
#define NPROD 4
#define PTILE 1024                  // edges per step
#define STEPS 33                    // steps per block
#define BPS   31                    // blocks per system: 31*33*1024 == EPS
#define GRID  (N_SYS * BPS)         // 248 blocks -> 1 per CU, single round
#define CLPAD (N_AT + N_AT / 8)     // 1152: padded scalar SoA, stride-4 gather ~2-way
#define OB4   (PTILE * 5 / 4)       // 1280 float4 per buffer

typedef float floatx4 __attribute__((ext_vector_type(4)));
typedef float floatx2 __attribute__((ext_vector_type(2)));

__device__ __forceinline__ unsigned pidx(unsigned b) { return b + (b >> 3); }

// 4 producer waves compute 1024 edges/step into a double-buffered LDS output
// image; 4 consumer waves stream ds_read_b128 -> dense global_store_dwordx4.
// In-loop sync is raw s_barrier + lgkmcnt(0) ONLY: stores are never drained
// inside the loop (no vmcnt(0)), so the HBM write queue stays full across
// steps -- the fix for R7's per-step store-drain stall.
__global__ __launch_bounds__(BLOCKT, 1) void graph_edges_pc(
    const float* __restrict__ coords,
    float*       __restrict__ out)
{
    __shared__ float clx[CLPAD];        // 13.8 KB total: scalar padded SoA
    __shared__ float cly[CLPAD];
    __shared__ float clz[CLPAD];
    __shared__ floatx4 obuf[2][OB4];    // 40 KB: double-buffered 1024-edge image

    const float PI_OVER_C = 3.14159265358979323846f / CUTOFF;
    const int t = threadIdx.x;
    const int w = t >> 6;               // wave id 0..7
    const int l = t & 63;               // lane id
    const int bb = blockIdx.x;
    const unsigned sys  = (unsigned)bb / BPS;        // magic-mul
    const unsigned bidx = (unsigned)bb - sys * BPS;  // 0..30 within system
    const unsigned rblock = bidx * (STEPS * PTILE);  // edge offset in system

    // ---- stage this system's coords once: thread t -> atoms 2t, 2t+1 ----
    {
        const floatx2* g2 = (const floatx2*)(coords + (size_t)sys * (3u * N_AT));
        floatx2 p0 = g2[3 * t + 0];
        floatx2 p1 = g2[3 * t + 1];
        floatx2 p2 = g2[3 * t + 2];
        unsigned a0 = 2u * (unsigned)t;
        unsigned i0 = pidx(a0), i1 = pidx(a0 + 1);
        clx[i0] = p0[0]; cly[i0] = p0[1]; clz[i0] = p1[0];
        clx[i1] = p1[1]; cly[i1] = p2[0]; clz[i1] = p2[1];
    }
    __syncthreads();                    // one-time full barrier (drain OK here)

    auto produce = [&](int s, int dst) {
        const unsigned r0 = rblock + (unsigned)s * PTILE
                          + ((unsigned)w << 8) + 4u * (unsigned)l;
        unsigned a = r0 / 1023u;        // magic-mul once; then incremental
        unsigned m = r0 - a * 1023u;
        float vals[20];
#pragma unroll
        for (int k = 0; k < 4; ++k) {
            unsigned b = m + (m >= a ? 1u : 0u);
            unsigned ia = pidx(a);      // ~wave-uniform -> broadcast
            unsigned ib = pidx(b);      // stride-4 padded -> ~2-way, free
            float x = clx[ib] - clx[ia];
            float y = cly[ib] - cly[ia];
            float z = clz[ib] - clz[ia];
            float d = sqrtf(x * x + y * y + z * z);
            float c = 0.5f * __cosf(d * PI_OVER_C) + 0.5f;
            vals[5 * k + 0] = x; vals[5 * k + 1] = y; vals[5 * k + 2] = z;
            vals[5 * k + 3] = d; vals[5 * k + 4] = (d < CUTOFF) ? c : 0.0f;
            ++m; if (m >= 1023u) { m = 0u; ++a; }
        }
        const int wb = w * 320 + 5 * l; // bank-tiling verified (R6)
#pragma unroll
        for (int q = 0; q < 5; ++q) {
            floatx4 o = { vals[4 * q + 0], vals[4 * q + 1],
                          vals[4 * q + 2], vals[4 * q + 3] };
            obuf[dst][wb + q] = o;
        }
    };

    // ---- prologue: produce step 0 into buf 0 ----
    if (w < NPROD) produce(0, 0);
    asm volatile("s_waitcnt lgkmcnt(0)" ::: "memory");
    __builtin_amdgcn_s_barrier();
    asm volatile("" ::: "memory");

    int cur = 0;
    for (int s = 0; s < STEPS; ++s) {
        if (w < NPROD) {
            if (s + 1 < STEPS) produce(s + 1, cur ^ 1);
        } else {
            // consumers: pure streaming drain of obuf[cur] -> dense stores
            const int o0 = (w - NPROD) * 64 + l;
            floatx4* out4 = (floatx4*)out
                          + (size_t)sys * (size_t)(EPS * 5 / 4)
                          + (size_t)(rblock + (unsigned)s * PTILE) * 5u / 4u;
#pragma unroll
            for (int r = 0; r < 5; ++r) {
                floatx4 v = obuf[cur][r * 256 + o0];
                out4[r * 256 + o0] = v;
            }
        }
        // raw barrier: wait LDS only; stores stay in flight across steps
        asm volatile("s_waitcnt lgkmcnt(0)" ::: "memory");
        __builtin_amdgcn_s_barrier();
        asm volatile("" ::: "memory");
        cur ^= 1;
    }
}

// General fallback: reads index arrays (round-1 verified kernel).
__global__ __launch_bounds__(256) void graph_edges_general(
    const float* __restrict__ coords,
    const int*   __restrict__ esrc,
    const int*   __restrict__ edst,
    float*       __restrict__ out,
    int E)
{
    __shared__ float buf[256 * 5];
    const float PI_OVER_C = 3.14159265358979323846f / CUTOFF;
    const int t = threadIdx.x;

    for (int base = blockIdx.x * 256; base < E; base += gridDim.x * 256) {
        int e = base + t;
        float vx = 0.f, vy = 0.f, vz = 0.f, d = 0.f, sw = 0.f;
        if (e < E) {
            int s  = esrc[e];
            int dd = edst[e];
            float sx = coords[3 * s + 0];
            float sy = coords[3 * s + 1];
            float sz = coords[3 * s + 2];
            float tx = coords[3 * dd + 0];
            float ty = coords[3 * dd + 1];
            float tz = coords[3 * dd + 2];
            vx = tx - sx; vy = ty - sy; vz = tz - sz;
            d = sqrtf(vx * vx + vy * vy + vz * vz);
            sw = (d < CUTOFF) ? (0.5f * __cosf(d * PI_OVER_C) + 0.5f) : 0.0f;
        }
        buf[t * 5 + 0] = vx;
        buf[t * 5 + 1] = vy;
        buf[t * 5 + 2] = vz;
        buf[t * 5 + 3] = d;
        buf[t * 5 + 4] = sw;
        __syncthreads();
        int remaining = E - base;
        int n = (remaining < 256 ? remaining : 256) * 5;
        int ob = base * 5;
        for (int k = t; k < n; k += 256) {
            out[ob + k] = buf[k];
        }
        __syncthreads();
    }
}

extern "C" void kernel_launch(void* const* d_in, const int* in_sizes, int n_in,
                              void* d_out, int out_size, void* d_ws, size_t ws_size,
                              hipStream_t stream) {
    const float* coords = (const float*)d_in[0];
    const int*   esrc   = (const int*)d_in[1];
    const int*   edst   = (const int*)d_in[2];
    float*       out    = (float*)d_out;

    int E = in_sizes[1];

    if (E == N_SYS * EPS) {
        graph_edges_pc<<<GRID, BLOCKT, 0, stream>>>(coords, out);
    } else {
        int blocks_needed = (E + 255) / 256;
        int grid = blocks_needed < 2048 ? blocks_needed : 2048;
        graph_edges_general<<<grid, 256, 0, stream>>>(coords, esrc, edst, out, E);
    }
}

// Round 9
// 31.999 us; speedup vs baseline: 1.0384x; 1.0384x over previous
//
#include <hip/hip_runtime.h>
#include <math.h>

#define CUTOFF 5.0f

#define N_SYS 8
#define N_AT  1024
#define EPS   (N_AT * (N_AT - 1))   // 1047552 edges per system

// ---- producer-consumer structured kernel geometry (R7 winning config) ----
#define PC_BLOCK 512                // 8 waves: 6 producers + 2 consumers
#define NPROD 6
#define PTILE (NPROD * 256)         // 1536 edges per step
#define STEPS 11                    // steps per block
#define BPS   62                    // blocks per system: 62*11*1536 == EPS
#define GRID  (N_SYS * BPS)         // 496 blocks -> 2 per CU
#define CLPAD 1152                  // N_AT + N_AT/8, padded float4 SoA
#define OB4   (PTILE * 5 / 4)       // 1920 float4 per buffer

typedef float floatx4 __attribute__((ext_vector_type(4)));

__device__ __forceinline__ unsigned pidx(unsigned b) { return b + (b >> 3); }

// R7 structure with ONE change: in-loop sync is raw s_barrier + lgkmcnt(0)
// instead of __syncthreads() (which drains vmcnt(0)). Consumer stores stay
// in flight across steps; consumers reach the barrier as soon as their LDS
// reads land, instead of stalling on HBM store acknowledgment every step.
__global__ __launch_bounds__(PC_BLOCK, 4) void graph_edges_pc(
    const float* __restrict__ coords,
    float*       __restrict__ out)
{
    __shared__ floatx4 cl4[CLPAD];      // 18.4 KB: one system, (x,y,z,0) padded
    __shared__ floatx4 obuf[2][OB4];    // 60 KB: double-buffered 1536-edge image

    const float PI_OVER_C = 3.14159265358979323846f / CUTOFF;
    const int t  = threadIdx.x;
    const int w  = t >> 6;              // wave id 0..7
    const int l  = t & 63;              // lane id
    const int bb = blockIdx.x;
    const unsigned sys  = (unsigned)bb / BPS;        // magic-mul
    const unsigned bidx = (unsigned)bb - sys * BPS;  // 0..61 within system

    // ---- stage this system's coords once (threads 0..255) ----
    if (t < 256) {
        const floatx4* g = (const floatx4*)(coords + (size_t)sys * (3u * N_AT));
        floatx4 v0 = g[3 * t + 0];
        floatx4 v1 = g[3 * t + 1];
        floatx4 v2 = g[3 * t + 2];
        float f[12] = { v0[0], v0[1], v0[2], v0[3],
                        v1[0], v1[1], v1[2], v1[3],
                        v2[0], v2[1], v2[2], v2[3] };
        unsigned a0 = 4u * (unsigned)t;
#pragma unroll
        for (int i = 0; i < 4; ++i) {
            floatx4 c = { f[3 * i + 0], f[3 * i + 1], f[3 * i + 2], 0.0f };
            cl4[pidx(a0 + i)] = c;
        }
    }
    __syncthreads();                    // one-time; drain harmless here

    const unsigned rblock = (bidx * STEPS) * (unsigned)PTILE;  // edge offset in system

    auto produce = [&](int s, int dst) {
        const unsigned r0 = rblock + (unsigned)s * PTILE
                          + ((unsigned)w << 8) + 4u * (unsigned)l;
        unsigned a = r0 / 1023u;                 // magic-mul once
        unsigned m = r0 - a * 1023u;
        float vals[20];
#pragma unroll
        for (int k = 0; k < 4; ++k) {
            unsigned b = m + (m >= a ? 1u : 0u);
            floatx4 ca = cl4[pidx(a)];           // ~broadcast
            floatx4 cb = cl4[pidx(b)];           // stride-4 padded -> ~2-way
            float x = cb[0] - ca[0], y = cb[1] - ca[1], z = cb[2] - ca[2];
            float d = sqrtf(x * x + y * y + z * z);
            float c = 0.5f * __cosf(d * PI_OVER_C) + 0.5f;
            vals[5 * k + 0] = x; vals[5 * k + 1] = y; vals[5 * k + 2] = z;
            vals[5 * k + 3] = d; vals[5 * k + 4] = (d < CUTOFF) ? c : 0.0f;
            ++m; if (m >= 1023u) { m = 0u; ++a; }
        }
        const int wb = w * 320 + 5 * l;          // bank-tiling verified (R6)
#pragma unroll
        for (int q = 0; q < 5; ++q) {
            floatx4 o = { vals[4 * q + 0], vals[4 * q + 1],
                          vals[4 * q + 2], vals[4 * q + 3] };
            obuf[dst][wb + q] = o;
        }
    };

    // ---- prologue: produce step 0 into buf 0 ----
    if (w < NPROD) produce(0, 0);
    asm volatile("s_waitcnt lgkmcnt(0)" ::: "memory");
    __builtin_amdgcn_s_barrier();
    asm volatile("" ::: "memory");

    int cur = 0;
    for (int s = 0; s < STEPS; ++s) {
        if (w < NPROD) {
            if (s + 1 < STEPS) produce(s + 1, cur ^ 1);
        } else {
            // consumers: pure streaming drain of obuf[cur] -> dense stores
            const int cw = w - NPROD;            // 0..1
            floatx4* out4 = (floatx4*)out
                          + (size_t)sys * (size_t)(EPS * 5 / 4)
                          + (size_t)(rblock + (unsigned)s * PTILE) * 5u / 4u;
            const int o0 = cw * 64 + l;
#pragma unroll
            for (int r = 0; r < 15; ++r) {
                floatx4 v = obuf[cur][r * 128 + o0];
                out4[r * 128 + o0] = v;
            }
        }
        // raw barrier: wait LDS only; stores stay in flight across steps
        asm volatile("s_waitcnt lgkmcnt(0)" ::: "memory");
        __builtin_amdgcn_s_barrier();
        asm volatile("" ::: "memory");
        cur ^= 1;
    }
}

// General fallback: reads index arrays (round-1 verified kernel).
__global__ __launch_bounds__(256) void graph_edges_general(
    const float* __restrict__ coords,
    const int*   __restrict__ esrc,
    const int*   __restrict__ edst,
    float*       __restrict__ out,
    int E)
{
    __shared__ float buf[256 * 5];
    const float PI_OVER_C = 3.14159265358979323846f / CUTOFF;
    const int t = threadIdx.x;

    for (int base = blockIdx.x * 256; base < E; base += gridDim.x * 256) {
        int e = base + t;
        float vx = 0.f, vy = 0.f, vz = 0.f, d = 0.f, sw = 0.f;
        if (e < E) {
            int s  = esrc[e];
            int dd = edst[e];
            float sx = coords[3 * s + 0];
            float sy = coords[3 * s + 1];
            float sz = coords[3 * s + 2];
            float tx = coords[3 * dd + 0];
            float ty = coords[3 * dd + 1];
            float tz = coords[3 * dd + 2];
            vx = tx - sx; vy = ty - sy; vz = tz - sz;
            d = sqrtf(vx * vx + vy * vy + vz * vz);
            sw = (d < CUTOFF) ? (0.5f * __cosf(d * PI_OVER_C) + 0.5f) : 0.0f;
        }
        buf[t * 5 + 0] = vx;
        buf[t * 5 + 1] = vy;
        buf[t * 5 + 2] = vz;
        buf[t * 5 + 3] = d;
        buf[t * 5 + 4] = sw;
        __syncthreads();
        int remaining = E - base;
        int n = (remaining < 256 ? remaining : 256) * 5;
        int ob = base * 5;
        for (int k = t; k < n; k += 256) {
            out[ob + k] = buf[k];
        }
        __syncthreads();
    }
}

extern "C" void kernel_launch(void* const* d_in, const int* in_sizes, int n_in,
                              void* d_out, int out_size, void* d_ws, size_t ws_size,
                              hipStream_t stream) {
    const float* coords = (const float*)d_in[0];
    const int*   esrc   = (const int*)d_in[1];
    const int*   edst   = (const int*)d_in[2];
    float*       out    = (float*)d_out;

    int E = in_sizes[1];

    if (E == N_SYS * EPS) {
        graph_edges_pc<<<GRID, PC_BLOCK, 0, stream>>>(coords, out);
    } else {
        int blocks_needed = (E + 255) / 256;
        int grid = blocks_needed < 2048 ? blocks_needed : 2048;
        graph_edges_general<<<grid, 256, 0, stream>>>(coords, esrc, edst, out, E);
    }
}

// Round 10
// 31.839 us; speedup vs baseline: 1.0436x; 1.0050x over previous
//
#include <hip/hip_runtime.h>
#include <math.h>

#define CUTOFF 5.0f

#define N_SYS 8
#define N_AT  1024
#define EPS   (N_AT * (N_AT - 1))   // 1047552 edges per system

// ---- producer-consumer geometry: R7 tile/grid, wider block for occupancy ----
#define PC_BLOCK 768                // 12 waves: 6 producers + 6 consumers
#define NPROD 6
#define PTILE (NPROD * 256)         // 1536 edges per step (unchanged from R7)
#define STEPS 11                    // steps per block
#define BPS   62                    // blocks per system: 62*11*1536 == EPS
#define GRID  (N_SYS * BPS)         // 496 blocks -> 2 per CU (LDS-limited)
#define CLPAD 1152                  // N_AT + N_AT/8, padded float4 SoA
#define OB4   (PTILE * 5 / 4)       // 1920 float4 per buffer

typedef float floatx4 __attribute__((ext_vector_type(4)));

__device__ __forceinline__ unsigned pidx(unsigned b) { return b + (b >> 3); }

// R7/R9 structure, ONE change: block widened 512->768 (6P+2C -> 6P+6C).
// Producer work per CU identical (12 producer waves); the 8 extra waves/CU
// (16->24, 4->6 per SIMD) exist purely to hide the gather->sqrt/cos->write
// latency chain that R9 showed is the step critical path. Consumers now
// drain 5 float4 each (1920/6/64), same conflict-free 16B-lane-stride reads.
__global__ __launch_bounds__(PC_BLOCK, 6) void graph_edges_pc(
    const float* __restrict__ coords,
    float*       __restrict__ out)
{
    __shared__ floatx4 cl4[CLPAD];      // 18.4 KB: one system, (x,y,z,0) padded
    __shared__ floatx4 obuf[2][OB4];    // 60 KB: double-buffered 1536-edge image

    const float PI_OVER_C = 3.14159265358979323846f / CUTOFF;
    const int t  = threadIdx.x;
    const int w  = t >> 6;              // wave id 0..11
    const int l  = t & 63;              // lane id
    const int bb = blockIdx.x;
    const unsigned sys  = (unsigned)bb / BPS;        // magic-mul
    const unsigned bidx = (unsigned)bb - sys * BPS;  // 0..61 within system

    // ---- stage this system's coords once (threads 0..255) ----
    if (t < 256) {
        const floatx4* g = (const floatx4*)(coords + (size_t)sys * (3u * N_AT));
        floatx4 v0 = g[3 * t + 0];
        floatx4 v1 = g[3 * t + 1];
        floatx4 v2 = g[3 * t + 2];
        float f[12] = { v0[0], v0[1], v0[2], v0[3],
                        v1[0], v1[1], v1[2], v1[3],
                        v2[0], v2[1], v2[2], v2[3] };
        unsigned a0 = 4u * (unsigned)t;
#pragma unroll
        for (int i = 0; i < 4; ++i) {
            floatx4 c = { f[3 * i + 0], f[3 * i + 1], f[3 * i + 2], 0.0f };
            cl4[pidx(a0 + i)] = c;
        }
    }
    __syncthreads();                    // one-time; drain harmless here

    const unsigned rblock = (bidx * STEPS) * (unsigned)PTILE;  // edge offset in system

    auto produce = [&](int s, int dst) {
        const unsigned r0 = rblock + (unsigned)s * PTILE
                          + ((unsigned)w << 8) + 4u * (unsigned)l;
        unsigned a = r0 / 1023u;                 // magic-mul once
        unsigned m = r0 - a * 1023u;
        float vals[20];
#pragma unroll
        for (int k = 0; k < 4; ++k) {
            unsigned b = m + (m >= a ? 1u : 0u);
            floatx4 ca = cl4[pidx(a)];           // ~broadcast
            floatx4 cb = cl4[pidx(b)];           // stride-4 padded -> ~2-way
            float x = cb[0] - ca[0], y = cb[1] - ca[1], z = cb[2] - ca[2];
            float d = sqrtf(x * x + y * y + z * z);
            float c = 0.5f * __cosf(d * PI_OVER_C) + 0.5f;
            vals[5 * k + 0] = x; vals[5 * k + 1] = y; vals[5 * k + 2] = z;
            vals[5 * k + 3] = d; vals[5 * k + 4] = (d < CUTOFF) ? c : 0.0f;
            ++m; if (m >= 1023u) { m = 0u; ++a; }
        }
        const int wb = w * 320 + 5 * l;          // bank-tiling verified (R6)
#pragma unroll
        for (int q = 0; q < 5; ++q) {
            floatx4 o = { vals[4 * q + 0], vals[4 * q + 1],
                          vals[4 * q + 2], vals[4 * q + 3] };
            obuf[dst][wb + q] = o;
        }
    };

    // ---- prologue: produce step 0 into buf 0 ----
    if (w < NPROD) produce(0, 0);
    asm volatile("s_waitcnt lgkmcnt(0)" ::: "memory");
    __builtin_amdgcn_s_barrier();
    asm volatile("" ::: "memory");

    int cur = 0;
    for (int s = 0; s < STEPS; ++s) {
        if (w < NPROD) {
            if (s + 1 < STEPS) produce(s + 1, cur ^ 1);
        } else {
            // consumers: pure streaming drain of obuf[cur] -> dense stores
            const int cidx = (w - NPROD) * 64 + l;   // 0..383
            floatx4* out4 = (floatx4*)out
                          + (size_t)sys * (size_t)(EPS * 5 / 4)
                          + (size_t)(rblock + (unsigned)s * PTILE) * 5u / 4u;
#pragma unroll
            for (int r = 0; r < 5; ++r) {            // 5*384 = 1920 float4
                floatx4 v = obuf[cur][r * 384 + cidx];
                out4[r * 384 + cidx] = v;
            }
        }
        // raw barrier: wait LDS only; stores stay in flight across steps
        asm volatile("s_waitcnt lgkmcnt(0)" ::: "memory");
        __builtin_amdgcn_s_barrier();
        asm volatile("" ::: "memory");
        cur ^= 1;
    }
}

// General fallback: reads index arrays (round-1 verified kernel).
__global__ __launch_bounds__(256) void graph_edges_general(
    const float* __restrict__ coords,
    const int*   __restrict__ esrc,
    const int*   __restrict__ edst,
    float*       __restrict__ out,
    int E)
{
    __shared__ float buf[256 * 5];
    const float PI_OVER_C = 3.14159265358979323846f / CUTOFF;
    const int t = threadIdx.x;

    for (int base = blockIdx.x * 256; base < E; base += gridDim.x * 256) {
        int e = base + t;
        float vx = 0.f, vy = 0.f, vz = 0.f, d = 0.f, sw = 0.f;
        if (e < E) {
            int s  = esrc[e];
            int dd = edst[e];
            float sx = coords[3 * s + 0];
            float sy = coords[3 * s + 1];
            float sz = coords[3 * s + 2];
            float tx = coords[3 * dd + 0];
            float ty = coords[3 * dd + 1];
            float tz = coords[3 * dd + 2];
            vx = tx - sx; vy = ty - sy; vz = tz - sz;
            d = sqrtf(vx * vx + vy * vy + vz * vz);
            sw = (d < CUTOFF) ? (0.5f * __cosf(d * PI_OVER_C) + 0.5f) : 0.0f;
        }
        buf[t * 5 + 0] = vx;
        buf[t * 5 + 1] = vy;
        buf[t * 5 + 2] = vz;
        buf[t * 5 + 3] = d;
        buf[t * 5 + 4] = sw;
        __syncthreads();
        int remaining = E - base;
        int n = (remaining < 256 ? remaining : 256) * 5;
        int ob = base * 5;
        for (int k = t; k < n; k += 256) {
            out[ob + k] = buf[k];
        }
        __syncthreads();
    }
}

extern "C" void kernel_launch(void* const* d_in, const int* in_sizes, int n_in,
                              void* d_out, int out_size, void* d_ws, size_t ws_size,
                              hipStream_t stream) {
    const float* coords = (const float*)d_in[0];
    const int*   esrc   = (const int*)d_in[1];
    const int*   edst   = (const int*)d_in[2];
    float*       out    = (float*)d_out;

    int E = in_sizes[1];

    if (E == N_SYS * EPS) {
        graph_edges_pc<<<GRID, PC_BLOCK, 0, stream>>>(coords, out);
    } else {
        int blocks_needed = (E + 255) / 256;
        int grid = blocks_needed < 2048 ? blocks_needed : 2048;
        graph_edges_general<<<grid, 256, 0, stream>>>(coords, esrc, edst, out, E);
    }
}